// Round 1
// 451.907 us; speedup vs baseline: 1.1447x; 1.1447x over previous
//
#include <hip/hip_runtime.h>
#include <math.h>

#define BB 48
#define LL 512
#define DD 192
#define HH 6
#define DKK 32
#define HID 768
#define ROWS (BB * LL)
#define BLD ((size_t)ROWS * DD)
#define SCALE_ATT 0.17677669529663687f  // 1/sqrt(32)
#define MASKED_S (-25.0f)

typedef unsigned short ushort_t;
typedef unsigned int uint_t;
typedef __bf16 bf16x8 __attribute__((ext_vector_type(8)));
typedef float f32x4 __attribute__((ext_vector_type(4)));

union U4BF8 { uint4 u; bf16x8 b; };

__device__ __forceinline__ ushort_t f2bf(float f) {
  union { float f; uint_t u; } v; v.f = f;
  uint_t r = v.u + 0x7fffu + ((v.u >> 16) & 1u);
  return (ushort_t)(r >> 16);
}
__device__ __forceinline__ float bf2f(ushort_t u) {
  union { uint_t u; float f; } v; v.u = ((uint_t)u) << 16; return v.f;
}

// ---------------------------------------------------------------------------
__global__ __launch_bounds__(256) void pack_kernel(
    const float* __restrict__ wq, const float* __restrict__ wk,
    const float* __restrict__ wv, const float* __restrict__ wo,
    const float* __restrict__ w1, const float* __restrict__ w2,
    const float* __restrict__ bq, const float* __restrict__ bk,
    const float* __restrict__ bv,
    ushort_t* __restrict__ Wqkv, ushort_t* __restrict__ Wo,
    ushort_t* __restrict__ W1, ushort_t* __restrict__ W2,
    float* __restrict__ bqkv) {
  int i = blockIdx.x * 256 + threadIdx.x;
  if (i < 110592) {                       // Wqkv_t [576][192]
    int n2 = i / 192, k = i - n2 * 192;
    int part = n2 / 192, n = n2 - part * 192;
    const float* src = part == 0 ? wq : (part == 1 ? wk : wv);
    Wqkv[i] = f2bf(src[k * 192 + n]);
  } else if (i < 147456) {                // Wo_t [192][192]
    int j = i - 110592;
    int n = j / 192, k = j - n * 192;
    Wo[j] = f2bf(wo[k * 192 + n]);
  } else if (i < 294912) {                // W1_t [768][192]
    int j = i - 147456;
    int n = j / 192, k = j - n * 192;
    W1[j] = f2bf(w1[k * 768 + n]);
  } else if (i < 442368) {                // W2_t [192][768]
    int j = i - 294912;
    int n = j / 768, k = j - n * 768;
    W2[j] = f2bf(w2[k * 192 + n]);
  } else if (i < 442944) {                // bqkv [576]
    int j = i - 442368;
    bqkv[j] = j < 192 ? bq[j] : (j < 384 ? bk[j - 192] : bv[j - 384]);
  }
}

// ---------------------------------------------------------------------------
// Dual-side masked LayerNorm over 2*ROWS rows.
// ---------------------------------------------------------------------------
__global__ __launch_bounds__(64) void mln2_kernel(
    const float* __restrict__ x0, const float* __restrict__ x1,
    const float* __restrict__ res0, const float* __restrict__ res1,
    const int* __restrict__ v0, const int* __restrict__ v1,
    const float* __restrict__ g0, const float* __restrict__ be0,
    const float* __restrict__ g1, const float* __restrict__ be1,
    float* __restrict__ outf, ushort_t* __restrict__ outb) {
  int row = blockIdx.x;
  int side = row >= ROWS;
  int r = side ? row - ROWS : row;
  int lane = threadIdx.x;
  const float* x = (side ? x1 : x0) + (size_t)r * DD;
  const float* rp = side ? res1 : res0;
  const float* g = side ? g1 : g0;
  const float* be = side ? be1 : be0;
  float v0_ = x[lane], v1_ = x[lane + 64], v2_ = x[lane + 128];
  if (rp != nullptr) {
    const float* rr = rp + (size_t)r * DD;
    v0_ += rr[lane]; v1_ += rr[lane + 64]; v2_ += rr[lane + 128];
  }
  float s = v0_ + v1_ + v2_;
#pragma unroll
  for (int off = 32; off; off >>= 1) s += __shfl_xor(s, off);
  float mu = s * (1.0f / 192.0f);
  float d0 = v0_ - mu, d1 = v1_ - mu, d2 = v2_ - mu;
  float ss = d0 * d0 + d1 * d1 + d2 * d2;
#pragma unroll
  for (int off = 32; off; off >>= 1) ss += __shfl_xor(ss, off);
  float inv = rsqrtf(ss * (1.0f / 192.0f) + 1e-5f);
  float r0, r1, r2;
  if ((side ? v1 : v0)[r]) {
    r0 = d0 * inv * g[lane]       + be[lane];
    r1 = d1 * inv * g[lane + 64]  + be[lane + 64];
    r2 = d2 * inv * g[lane + 128] + be[lane + 128];
  } else {
    r0 = v0_; r1 = v1_; r2 = v2_;
  }
  size_t o = (size_t)row * DD;
  if (outf != nullptr) {
    outf[o + lane] = r0; outf[o + lane + 64] = r1; outf[o + lane + 128] = r2;
  }
  if (outb != nullptr) {
    outb[o + lane] = f2bf(r0); outb[o + lane + 64] = f2bf(r1);
    outb[o + lane + 128] = f2bf(r2);
  }
}

// ---------------------------------------------------------------------------
// Fused chain: y = mln(t + res, ln_oX) -> outf; z = mln(y, fln) -> outb.
// ---------------------------------------------------------------------------
__global__ __launch_bounds__(64) void mln_chain_kernel(
    const float* __restrict__ t,
    const float* __restrict__ res0, const float* __restrict__ res1,
    const int* __restrict__ v0, const int* __restrict__ v1,
    const float* __restrict__ g1a, const float* __restrict__ b1a,
    const float* __restrict__ g1b, const float* __restrict__ b1b,
    const float* __restrict__ g2, const float* __restrict__ b2,
    float* __restrict__ outf, ushort_t* __restrict__ outb) {
  int row = blockIdx.x;
  int side = row >= ROWS;
  int r = side ? row - ROWS : row;
  int lane = threadIdx.x;
  const float* tr = t + (size_t)row * DD;
  const float* rr = (side ? res1 : res0) + (size_t)r * DD;
  const float* g1 = side ? g1b : g1a;
  const float* b1 = side ? b1b : b1a;
  int vld = (side ? v1 : v0)[r];
  float v0_ = tr[lane] + rr[lane];
  float v1_ = tr[lane + 64] + rr[lane + 64];
  float v2_ = tr[lane + 128] + rr[lane + 128];
  float s = v0_ + v1_ + v2_;
#pragma unroll
  for (int off = 32; off; off >>= 1) s += __shfl_xor(s, off);
  float mu = s * (1.0f / 192.0f);
  float d0 = v0_ - mu, d1 = v1_ - mu, d2 = v2_ - mu;
  float ss = d0 * d0 + d1 * d1 + d2 * d2;
#pragma unroll
  for (int off = 32; off; off >>= 1) ss += __shfl_xor(ss, off);
  float inv = rsqrtf(ss * (1.0f / 192.0f) + 1e-5f);
  float y0, y1, y2;
  if (vld) {
    y0 = d0 * inv * g1[lane]       + b1[lane];
    y1 = d1 * inv * g1[lane + 64]  + b1[lane + 64];
    y2 = d2 * inv * g1[lane + 128] + b1[lane + 128];
  } else { y0 = v0_; y1 = v1_; y2 = v2_; }
  size_t o = (size_t)row * DD;
  outf[o + lane] = y0; outf[o + lane + 64] = y1; outf[o + lane + 128] = y2;
  float s2 = y0 + y1 + y2;
#pragma unroll
  for (int off = 32; off; off >>= 1) s2 += __shfl_xor(s2, off);
  float mu2 = s2 * (1.0f / 192.0f);
  float e0 = y0 - mu2, e1 = y1 - mu2, e2 = y2 - mu2;
  float ss2 = e0 * e0 + e1 * e1 + e2 * e2;
#pragma unroll
  for (int off = 32; off; off >>= 1) ss2 += __shfl_xor(ss2, off);
  float inv2 = rsqrtf(ss2 * (1.0f / 192.0f) + 1e-5f);
  float z0, z1, z2;
  if (vld) {
    z0 = e0 * inv2 * g2[lane]       + b2[lane];
    z1 = e1 * inv2 * g2[lane + 64]  + b2[lane + 64];
    z2 = e2 * inv2 * g2[lane + 128] + b2[lane + 128];
  } else { z0 = y0; z1 = y1; z2 = y2; }
  outb[o + lane] = f2bf(z0); outb[o + lane + 64] = f2bf(z1);
  outb[o + lane + 128] = f2bf(z2);
}

// ---------------------------------------------------------------------------
// bf16 MFMA GEMM, 1D grid with XCD swizzle: xcd = id&7 owns a contiguous
// band of row-tiles x ALL col-tiles -> A rows fetched once per XCD.
// ny (=M/128) must be divisible by 8.
// ---------------------------------------------------------------------------
__global__ __launch_bounds__(128) void gemm_mfma_kernel(
    const ushort_t* __restrict__ A, const ushort_t* __restrict__ Wt,
    const float* __restrict__ bias, float* __restrict__ Cf,
    ushort_t* __restrict__ Cb, int M, int N, int K, int gelu, int nx) {
  __shared__ ushort_t As[128 * 40];
  __shared__ ushort_t Bs[64 * 40];
  int id = blockIdx.x;
  int ny8 = (M / 128) >> 3;
  int xcd = id & 7;
  int s = id >> 3;
  int cy = xcd * ny8 + s / nx;
  int cx = s % nx;
  int tid = threadIdx.x;
  int lane = tid & 63;
  int w = tid >> 6;
  int row0 = cy * 128;
  int col0 = cx * 64;
  int l15 = lane & 15;
  int kq = lane >> 4;

  int lr = tid >> 2, lq = tid & 3;
  int lr2 = (tid + 128) >> 2, lq2 = (tid + 128) & 3;
  int nr = tid >> 2, nq = tid & 3;

  f32x4 acc[4][4];
#pragma unroll
  for (int i = 0; i < 4; ++i)
#pragma unroll
    for (int j = 0; j < 4; ++j) acc[i][j] = (f32x4){0.f, 0.f, 0.f, 0.f};

#define LOADAB(AV, BV, K0)                                                   \
  {                                                                          \
    AV[0] = *(const uint4*)(A + (size_t)(row0 + lr) * K + (K0) + lq * 8);    \
    AV[1] = *(const uint4*)(A + (size_t)(row0 + lr2) * K + (K0) + lq2 * 8);  \
    AV[2] = *(const uint4*)(A + (size_t)(row0 + lr + 64) * K + (K0) + lq * 8);   \
    AV[3] = *(const uint4*)(A + (size_t)(row0 + lr2 + 64) * K + (K0) + lq2 * 8); \
    BV[0] = *(const uint4*)(Wt + (size_t)(col0 + nr) * K + (K0) + nq * 8);   \
    BV[1] = *(const uint4*)(Wt + (size_t)(col0 + nr + 32) * K + (K0) + nq * 8);  \
  }

#define STOREAB(AV, BV)                                                      \
  {                                                                          \
    *(uint4*)(&As[lr * 40 + lq * 8]) = AV[0];                                \
    *(uint4*)(&As[lr2 * 40 + lq2 * 8]) = AV[1];                              \
    *(uint4*)(&As[(lr + 64) * 40 + lq * 8]) = AV[2];                         \
    *(uint4*)(&As[(lr2 + 64) * 40 + lq2 * 8]) = AV[3];                       \
    *(uint4*)(&Bs[nr * 40 + nq * 8]) = BV[0];                                \
    *(uint4*)(&Bs[(nr + 32) * 40 + nq * 8]) = BV[1];                         \
  }

#define COMPUTE()                                                            \
  {                                                                          \
    bf16x8 af[4], bf[4];                                                     \
    _Pragma("unroll") for (int mt = 0; mt < 4; ++mt)                         \
      af[mt] = *(const bf16x8*)(&As[(w * 64 + mt * 16 + l15) * 40 + kq * 8]);\
    _Pragma("unroll") for (int nt = 0; nt < 4; ++nt)                         \
      bf[nt] = *(const bf16x8*)(&Bs[(nt * 16 + l15) * 40 + kq * 8]);         \
    _Pragma("unroll") for (int mt = 0; mt < 4; ++mt)                         \
      _Pragma("unroll") for (int nt = 0; nt < 4; ++nt)                       \
        acc[mt][nt] = __builtin_amdgcn_mfma_f32_16x16x32_bf16(               \
            af[mt], bf[nt], acc[mt][nt], 0, 0, 0);                           \
  }

  int iters = K >> 5;
  uint4 avA[4], bvA[2], avB[4], bvB[2];
  LOADAB(avA, bvA, 0)
  for (int it = 0; it < iters; it += 2) {
    __syncthreads();
    STOREAB(avA, bvA)
    __syncthreads();
    if (it + 1 < iters) LOADAB(avB, bvB, (it + 1) << 5)
    COMPUTE()
    __syncthreads();
    STOREAB(avB, bvB)
    __syncthreads();
    if (it + 2 < iters) LOADAB(avA, bvA, (it + 2) << 5)
    COMPUTE()
  }
#undef LOADAB
#undef STOREAB
#undef COMPUTE

  float bcol[4];
#pragma unroll
  for (int nt = 0; nt < 4; ++nt) bcol[nt] = bias[col0 + nt * 16 + l15];
#pragma unroll
  for (int mt = 0; mt < 4; ++mt) {
#pragma unroll
    for (int nt = 0; nt < 4; ++nt) {
      int col = col0 + nt * 16 + l15;
#pragma unroll
      for (int r = 0; r < 4; ++r) {
        int row = row0 + w * 64 + mt * 16 + kq * 4 + r;
        float x = acc[mt][nt][r] + bcol[nt];
        if (gelu) x = 0.5f * x * (1.0f + erff(x * 0.70710678118654752f));
        if (Cf != nullptr) Cf[(size_t)row * N + col] = x;
        else Cb[(size_t)row * N + col] = f2bf(x);
      }
    }
  }
}

// ---------------------------------------------------------------------------
// Fused FFN, v2: 256 threads (4 waves), 64 rows/block, N-split decomposition.
//   H phase: wave w computes H[0..63][w*16..w*16+15]  (reads 1/4 of W1)
//   C phase: wave w computes C[0..63][w*48..w*48+47]  (reads 1/4 of W2)
// -> 12 waves/CU occupancy (3 blocks/CU by LDS), weights read once per BLOCK
//    (was once per wave), one barrier per hc via double-buffered Hs.
// W1/W2 fragments prefetched across the barrier to hide L2 latency.
// ---------------------------------------------------------------------------
__global__ __launch_bounds__(256, 3) void ffn_fused_kernel(
    const ushort_t* __restrict__ A, const ushort_t* __restrict__ W1t,
    const float* __restrict__ bias1, const ushort_t* __restrict__ W2t,
    const float* __restrict__ bias2, float* __restrict__ C) {
  __shared__ ushort_t As[64 * 200];      // [row][k], pad 192->200 (25.6 KB)
  __shared__ ushort_t Hs[2][64 * 72];    // shared hidden chunk, dbuf (18.4 KB)
  int tid = threadIdx.x;
  int w = tid >> 6;
  int lane = tid & 63;
  int l15 = lane & 15;
  int kq = lane >> 4;
  int row0 = blockIdx.x * 64;

  // stage A: 64 rows x 24 uint4 = 1536 / 256 threads = 6 each
#pragma unroll
  for (int i = 0; i < 6; ++i) {
    int idx = tid + i * 256;
    int r = idx / 24, c = (idx % 24) * 8;
    *(uint4*)(&As[r * 200 + c]) = *(const uint4*)(A + (size_t)(row0 + r) * DD + c);
  }

  // per-wave weight base pointers
  const ushort_t* w1p = W1t + (size_t)(w * 16 + l15) * DD + kq * 8;   // + hc*64*DD + kk*32
  const ushort_t* w2p = W2t + (size_t)(w * 48 + l15) * HID + kq * 8;  // + nt*16*HID + hc*64 + kk2*32

  U4BF8 w1f[6], w1n[6], w2f[6];
#pragma unroll
  for (int kk = 0; kk < 6; ++kk)
    w1f[kk].u = *(const uint4*)(w1p + kk * 32);  // hc = 0

  f32x4 Cacc[4][3];
#pragma unroll
  for (int qs = 0; qs < 4; ++qs)
#pragma unroll
    for (int nt = 0; nt < 3; ++nt) Cacc[qs][nt] = (f32x4){0.f, 0.f, 0.f, 0.f};

  __syncthreads();   // As ready

  for (int hc = 0; hc < 12; ++hc) {
    // issue W2 fragments for this hc early: latency hides under H phase
#pragma unroll
    for (int kk2 = 0; kk2 < 2; ++kk2)
#pragma unroll
      for (int nt = 0; nt < 3; ++nt)
        w2f[kk2 * 3 + nt].u =
            *(const uint4*)(w2p + (size_t)(nt * 16) * HID + hc * 64 + kk2 * 32);

    // --- H[0..63][w*16..+15] = A @ W1 chunk ---
    f32x4 Hacc[4];
#pragma unroll
    for (int qs = 0; qs < 4; ++qs) Hacc[qs] = (f32x4){0.f, 0.f, 0.f, 0.f};
#pragma unroll
    for (int kk = 0; kk < 6; ++kk) {
#pragma unroll
      for (int qs = 0; qs < 4; ++qs) {
        bf16x8 af = *(const bf16x8*)(&As[(qs * 16 + l15) * 200 + kk * 32 + kq * 8]);
        Hacc[qs] = __builtin_amdgcn_mfma_f32_16x16x32_bf16(
            af, w1f[kk].b, Hacc[qs], 0, 0, 0);
      }
    }

    // prefetch next hc's W1 fragments: latency hides under gelu+barrier+C
    if (hc < 11) {
#pragma unroll
      for (int kk = 0; kk < 6; ++kk)
        w1n[kk].u = *(const uint4*)(w1p + (size_t)(hc + 1) * 64 * DD + kk * 32);
    }

    // --- gelu + bias -> Hs[buf] (this wave's 16 columns, all 64 rows) ---
    {
      float bb = bias1[hc * 64 + w * 16 + l15];
      ushort_t* hb = &Hs[hc & 1][0];
#pragma unroll
      for (int qs = 0; qs < 4; ++qs)
#pragma unroll
        for (int r = 0; r < 4; ++r) {
          float x = Hacc[qs][r] + bb;
          x = 0.5f * x * (1.0f + erff(x * 0.70710678118654752f));
          hb[(qs * 16 + kq * 4 + r) * 72 + w * 16 + l15] = f2bf(x);
        }
    }
    __syncthreads();   // Hs[buf] complete; also fences reads of Hs[buf^1]

    // --- C[0..63][w*48..+47] += H @ W2 chunk ---
#pragma unroll
    for (int kk2 = 0; kk2 < 2; ++kk2) {
      bf16x8 hf[4];
#pragma unroll
      for (int qs = 0; qs < 4; ++qs)
        hf[qs] = *(const bf16x8*)(&Hs[hc & 1][(qs * 16 + l15) * 72 + kk2 * 32 + kq * 8]);
#pragma unroll
      for (int nt = 0; nt < 3; ++nt)
#pragma unroll
        for (int qs = 0; qs < 4; ++qs)
          Cacc[qs][nt] = __builtin_amdgcn_mfma_f32_16x16x32_bf16(
              hf[qs], w2f[kk2 * 3 + nt].b, Cacc[qs][nt], 0, 0, 0);
    }

#pragma unroll
    for (int kk = 0; kk < 6; ++kk) w1f[kk] = w1n[kk];
  }

  // epilogue
#pragma unroll
  for (int qs = 0; qs < 4; ++qs)
#pragma unroll
    for (int nt = 0; nt < 3; ++nt) {
      int col = w * 48 + nt * 16 + l15;
      float bb = bias2[col];
#pragma unroll
      for (int r = 0; r < 4; ++r) {
        int row = row0 + qs * 16 + kq * 4 + r;
        C[(size_t)row * DD + col] = Cacc[qs][nt][r] + bb;
      }
    }
}

// ---------------------------------------------------------------------------
// MFMA flash attention (validated R6/R7): both sides, no online max,
// XCD swizzle groups q-tiles of one (b,h,side).
// ---------------------------------------------------------------------------
__global__ __launch_bounds__(256) void attn_mfma_kernel(
    const ushort_t* __restrict__ QKV,
    const int* __restrict__ valid_a, const int* __restrict__ valid_b,
    ushort_t* __restrict__ out) {
  int i = blockIdx.x;
  int gid = ((i >> 5) << 3) | (i & 7);
  int qt = (i >> 3) & 3;
  int side = gid >= BB * HH;
  int grem = side ? gid - BB * HH : gid;
  int h = grem % HH;
  int batch = grem / HH;
  int tid = threadIdx.x;
  int w = tid >> 6;
  int lane = tid & 63;
  int l15 = lane & 15;
  int kq = lane >> 4;

  const int* validq = side ? valid_b : valid_a;
  const int* validk = side ? valid_a : valid_b;
  size_t qrow0  = (size_t)side * ROWS + (size_t)batch * LL;
  size_t kvrow0 = (size_t)(1 - side) * ROWS + (size_t)batch * LL;

  __shared__ ushort_t VsT[32 * 72];
  __shared__ ushort_t Ps[4][32 * 72];

  int qbase = qt * 128 + w * 32;

  U4BF8 qfrag[2];
#pragma unroll
  for (int qs = 0; qs < 2; ++qs)
    qfrag[qs].u = *(const uint4*)(QKV + (qrow0 + qbase + qs * 16 + l15) * 576 +
                                  h * DKK + kq * 8);

  int vq[2][4];
#pragma unroll
  for (int qs = 0; qs < 2; ++qs)
#pragma unroll
    for (int r = 0; r < 4; ++r)
      vq[qs][r] = validq[batch * LL + qbase + qs * 16 + kq * 4 + r];

  float lsum[2][4];
  f32x4 Oacc[2][2];
#pragma unroll
  for (int qs = 0; qs < 2; ++qs) {
#pragma unroll
    for (int r = 0; r < 4; ++r) lsum[qs][r] = 0.0f;
#pragma unroll
    for (int ds = 0; ds < 2; ++ds) Oacc[qs][ds] = (f32x4){0.f, 0.f, 0.f, 0.f};
  }

  for (int c = 0; c < LL; c += 64) {
    __syncthreads();
    uint4 vv = *(const uint4*)(QKV + (kvrow0 + c + lane) * 576 +
                               384 + h * DKK + w * 8);
    uint_t uu[4] = {vv.x, vv.y, vv.z, vv.w};
#pragma unroll
    for (int j = 0; j < 4; ++j) {
      VsT[(w * 8 + 2 * j) * 72 + lane]     = (ushort_t)(uu[j] & 0xffffu);
      VsT[(w * 8 + 2 * j + 1) * 72 + lane] = (ushort_t)(uu[j] >> 16);
    }
    __syncthreads();

    f32x4 S[2][4];
    int vk[4];
#pragma unroll
    for (int ks = 0; ks < 4; ++ks) {
      U4BF8 kf;
      kf.u = *(const uint4*)(QKV + (kvrow0 + c + ks * 16 + l15) * 576 +
                             192 + h * DKK + kq * 8);
      vk[ks] = validk[batch * LL + c + ks * 16 + l15];
#pragma unroll
      for (int qs = 0; qs < 2; ++qs) {
        f32x4 z = (f32x4){0.f, 0.f, 0.f, 0.f};
        S[qs][ks] = __builtin_amdgcn_mfma_f32_16x16x32_bf16(
            qfrag[qs].b, kf.b, z, 0, 0, 0);
      }
    }

#pragma unroll
    for (int qs = 0; qs < 2; ++qs)
#pragma unroll
      for (int ks = 0; ks < 4; ++ks)
#pragma unroll
        for (int r = 0; r < 4; ++r) {
          float x = (vq[qs][r] && vk[ks]) ? S[qs][ks][r] * SCALE_ATT : MASKED_S;
          float p = __expf(x);
          ushort_t pb = f2bf(p);
          lsum[qs][r] += bf2f(pb);
          Ps[w][(qs * 16 + kq * 4 + r) * 72 + ks * 16 + l15] = pb;
        }

#pragma unroll
    for (int kh = 0; kh < 2; ++kh) {
      bf16x8 pf[2], vf[2];
#pragma unroll
      for (int qs = 0; qs < 2; ++qs)
        pf[qs] = *(const bf16x8*)(&Ps[w][(qs * 16 + l15) * 72 + kh * 32 + kq * 8]);
#pragma unroll
      for (int ds = 0; ds < 2; ++ds)
        vf[ds] = *(const bf16x8*)(&VsT[(ds * 16 + l15) * 72 + kh * 32 + kq * 8]);
#pragma unroll
      for (int qs = 0; qs < 2; ++qs)
#pragma unroll
        for (int ds = 0; ds < 2; ++ds)
          Oacc[qs][ds] = __builtin_amdgcn_mfma_f32_16x16x32_bf16(
              pf[qs], vf[ds], Oacc[qs][ds], 0, 0, 0);
    }
  }

#pragma unroll
  for (int qs = 0; qs < 2; ++qs)
#pragma unroll
    for (int r = 0; r < 4; ++r) {
      float sm = lsum[qs][r];
#pragma unroll
      for (int off = 1; off < 16; off <<= 1) sm += __shfl_xor(sm, off);
      lsum[qs][r] = sm;
    }

#pragma unroll
  for (int qs = 0; qs < 2; ++qs)
#pragma unroll
    for (int ds = 0; ds < 2; ++ds)
#pragma unroll
      for (int r = 0; r < 4; ++r) {
        int q = qbase + qs * 16 + kq * 4 + r;
        out[(qrow0 + q) * DD + h * DKK + ds * 16 + l15] =
            f2bf(Oacc[qs][ds][r] / lsum[qs][r]);
      }
}

// ---------------------------------------------------------------------------
extern "C" void kernel_launch(void* const* d_in, const int* in_sizes, int n_in,
                              void* d_out, int out_size, void* d_ws, size_t ws_size,
                              hipStream_t stream) {
  const float* x_a = (const float*)d_in[0];
  const float* x_b = (const float*)d_in[1];
  const int* valid_a = (const int*)d_in[2];
  const int* valid_b = (const int*)d_in[3];
  const float* ln_a_g = (const float*)d_in[4];
  const float* ln_a_b = (const float*)d_in[5];
  const float* ln_b_g = (const float*)d_in[6];
  const float* ln_b_b = (const float*)d_in[7];
  const float* ln_oa_g = (const float*)d_in[8];
  const float* ln_oa_b = (const float*)d_in[9];
  const float* ln_ob_g = (const float*)d_in[10];
  const float* ln_ob_b = (const float*)d_in[11];
  const float* wq = (const float*)d_in[12];
  const float* bq = (const float*)d_in[13];
  const float* wk = (const float*)d_in[14];
  const float* bk = (const float*)d_in[15];
  const float* wv = (const float*)d_in[16];
  const float* bv = (const float*)d_in[17];
  const float* wo = (const float*)d_in[18];
  const float* bo = (const float*)d_in[19];
  const float* fln_g = (const float*)d_in[20];
  const float* fln_b = (const float*)d_in[21];
  const float* flno_g = (const float*)d_in[22];
  const float* flno_b = (const float*)d_in[23];
  const float* w1 = (const float*)d_in[24];
  const float* b1 = (const float*)d_in[25];
  const float* w2 = (const float*)d_in[26];
  const float* b2 = (const float*)d_in[27];

  // Workspace: weights [0, 887040); lnFull/attO bf16 [2R,192] at 887040;
  // QKV bf16 [2R,576] at 19761408; tmp fp32 [2R,192] at 76384512. ~114 MB.
  char* wsb = (char*)d_ws;
  ushort_t* Wqkv = (ushort_t*)wsb;
  ushort_t* Wo_t = Wqkv + 110592;
  ushort_t* W1_t = Wo_t + 36864;
  ushort_t* W2_t = W1_t + 147456;
  float*    bqkv = (float*)(W2_t + 147456);
  ushort_t* lnFull = (ushort_t*)(wsb + 887040);
  ushort_t* attO   = lnFull;
  ushort_t* QKV = (ushort_t*)(wsb + 19761408);
  float* tmp = (float*)(wsb + 76384512);

  float* out_a = (float*)d_out;   // [2R,192] fp32 contiguous

  dim3 b64(64), b128(128), b256(256);
  dim3 gMln(2 * ROWS);
  dim3 gQKV(9 * (2 * ROWS / 128));              // 1D swizzled: nx=9
  dim3 gO(3 * (2 * ROWS / 128));                // nx=3
  dim3 gAttn(BB * HH * 4 * 2);                  // 2304
  dim3 gFFN(2 * ROWS / 64);                     // 768

  hipLaunchKernelGGL(pack_kernel, dim3(1731), b256, 0, stream,
                     wq, wk, wv, wo, w1, w2, bq, bk, bv,
                     Wqkv, Wo_t, W1_t, W2_t, bqkv);

  // 1. pre-LN both sides -> lnFull bf16
  hipLaunchKernelGGL(mln2_kernel, gMln, b64, 0, stream,
                     x_a, x_b, (const float*)nullptr, (const float*)nullptr,
                     valid_a, valid_b, ln_a_g, ln_a_b, ln_b_g, ln_b_b,
                     (float*)nullptr, lnFull);

  // 2. fused QKV, both sides
  hipLaunchKernelGGL(gemm_mfma_kernel, gQKV, b128, 0, stream,
                     lnFull, Wqkv, bqkv, (float*)nullptr, QKV,
                     2 * ROWS, 576, DD, 0, 9);

  // 3. attention, both sides
  hipLaunchKernelGGL(attn_mfma_kernel, gAttn, b256, 0, stream,
                     QKV, valid_a, valid_b, attO);

  // 4. O-projection, both sides -> tmp fp32
  hipLaunchKernelGGL(gemm_mfma_kernel, gO, b128, 0, stream,
                     attO, Wo_t, bo, tmp, (ushort_t*)nullptr,
                     2 * ROWS, DD, DD, 0, 3);

  // 5+6. fused residual-LN -> d_out, FFN pre-LN -> lnFull bf16
  hipLaunchKernelGGL(mln_chain_kernel, gMln, b64, 0, stream,
                     tmp, x_a, x_b, valid_a, valid_b,
                     ln_oa_g, ln_oa_b, ln_ob_g, ln_ob_b, fln_g, fln_b,
                     out_a, lnFull);

  // 7. fused FFN (no hidden round-trip), 4-wave N-split -> tmp fp32
  hipLaunchKernelGGL(ffn_fused_kernel, gFFN, b256, 0, stream,
                     lnFull, W1_t, b1, W2_t, b2, tmp);

  // 8. FFN residual + LN -> d_out
  hipLaunchKernelGGL(mln2_kernel, gMln, b64, 0, stream,
                     tmp, tmp + BLD, out_a, out_a + BLD,
                     valid_a, valid_b, flno_g, flno_b, flno_g, flno_b,
                     out_a, (ushort_t*)nullptr);
}

// Round 2
// 357.810 us; speedup vs baseline: 1.4457x; 1.2630x over previous
//
#include <hip/hip_runtime.h>
#include <math.h>

#define BB 48
#define LL 512
#define DD 192
#define HH 6
#define DKK 32
#define HID 768
#define ROWS (BB * LL)
#define BLD ((size_t)ROWS * DD)
#define SCALE_ATT 0.17677669529663687f  // 1/sqrt(32)
#define MASKED_S (-25.0f)

typedef unsigned short ushort_t;
typedef unsigned int uint_t;
typedef __bf16 bf16x8 __attribute__((ext_vector_type(8)));
typedef float f32x4 __attribute__((ext_vector_type(4)));

union U4BF8 { uint4 u; bf16x8 b; };

__device__ __forceinline__ ushort_t f2bf(float f) {
  union { float f; uint_t u; } v; v.f = f;
  uint_t r = v.u + 0x7fffu + ((v.u >> 16) & 1u);
  return (ushort_t)(r >> 16);
}
__device__ __forceinline__ float bf2f(ushort_t u) {
  union { uint_t u; float f; } v; v.u = ((uint_t)u) << 16; return v.f;
}

// Swizzled weight offset: fragment-major so a wave's dwordx4 load of one
// 16x32 (n x k) MFMA B-tile is lane-linear (fully coalesced 1KB/wave).
// offset = tile(k/32, n/16) * 512 + lane(kq,l15) * 8 + k%8
__device__ __forceinline__ int swz_w(int n, int k, int N) {
  return ((k >> 5) * (N >> 4) + (n >> 4)) * 512 +
         ((((k & 31) >> 3) << 4) + (n & 15)) * 8 + (k & 7);
}

// ---------------------------------------------------------------------------
__global__ __launch_bounds__(256) void pack_kernel(
    const float* __restrict__ wq, const float* __restrict__ wk,
    const float* __restrict__ wv, const float* __restrict__ wo,
    const float* __restrict__ w1, const float* __restrict__ w2,
    const float* __restrict__ bq, const float* __restrict__ bk,
    const float* __restrict__ bv,
    ushort_t* __restrict__ Wqkv, ushort_t* __restrict__ Wo,
    ushort_t* __restrict__ W1, ushort_t* __restrict__ W2,
    float* __restrict__ bqkv) {
  int i = blockIdx.x * 256 + threadIdx.x;
  if (i < 110592) {                       // Wqkv swizzled, N=576
    int n2 = i / 192, k = i - n2 * 192;
    int part = n2 / 192, n = n2 - part * 192;
    const float* src = part == 0 ? wq : (part == 1 ? wk : wv);
    Wqkv[swz_w(n2, k, 576)] = f2bf(src[k * 192 + n]);
  } else if (i < 147456) {                // Wo swizzled, N=192
    int j = i - 110592;
    int n = j / 192, k = j - n * 192;
    Wo[swz_w(n, k, 192)] = f2bf(wo[k * 192 + n]);
  } else if (i < 294912) {                // W1_t [768][192]
    int j = i - 147456;
    int n = j / 192, k = j - n * 192;
    W1[j] = f2bf(w1[k * 768 + n]);
  } else if (i < 442368) {                // W2_t [192][768]
    int j = i - 294912;
    int n = j / 768, k = j - n * 768;
    W2[j] = f2bf(w2[k * 192 + n]);
  } else if (i < 442944) {                // bqkv [576]
    int j = i - 442368;
    bqkv[j] = j < 192 ? bq[j] : (j < 384 ? bk[j - 192] : bv[j - 384]);
  }
}

// ---------------------------------------------------------------------------
// Dual-side masked LayerNorm over 2*ROWS rows.
// ---------------------------------------------------------------------------
__global__ __launch_bounds__(64) void mln2_kernel(
    const float* __restrict__ x0, const float* __restrict__ x1,
    const float* __restrict__ res0, const float* __restrict__ res1,
    const int* __restrict__ v0, const int* __restrict__ v1,
    const float* __restrict__ g0, const float* __restrict__ be0,
    const float* __restrict__ g1, const float* __restrict__ be1,
    float* __restrict__ outf, ushort_t* __restrict__ outb) {
  int row = blockIdx.x;
  int side = row >= ROWS;
  int r = side ? row - ROWS : row;
  int lane = threadIdx.x;
  const float* x = (side ? x1 : x0) + (size_t)r * DD;
  const float* rp = side ? res1 : res0;
  const float* g = side ? g1 : g0;
  const float* be = side ? be1 : be0;
  float v0_ = x[lane], v1_ = x[lane + 64], v2_ = x[lane + 128];
  if (rp != nullptr) {
    const float* rr = rp + (size_t)r * DD;
    v0_ += rr[lane]; v1_ += rr[lane + 64]; v2_ += rr[lane + 128];
  }
  float s = v0_ + v1_ + v2_;
#pragma unroll
  for (int off = 32; off; off >>= 1) s += __shfl_xor(s, off);
  float mu = s * (1.0f / 192.0f);
  float d0 = v0_ - mu, d1 = v1_ - mu, d2 = v2_ - mu;
  float ss = d0 * d0 + d1 * d1 + d2 * d2;
#pragma unroll
  for (int off = 32; off; off >>= 1) ss += __shfl_xor(ss, off);
  float inv = rsqrtf(ss * (1.0f / 192.0f) + 1e-5f);
  float r0, r1, r2;
  if ((side ? v1 : v0)[r]) {
    r0 = d0 * inv * g[lane]       + be[lane];
    r1 = d1 * inv * g[lane + 64]  + be[lane + 64];
    r2 = d2 * inv * g[lane + 128] + be[lane + 128];
  } else {
    r0 = v0_; r1 = v1_; r2 = v2_;
  }
  size_t o = (size_t)row * DD;
  if (outf != nullptr) {
    outf[o + lane] = r0; outf[o + lane + 64] = r1; outf[o + lane + 128] = r2;
  }
  if (outb != nullptr) {
    outb[o + lane] = f2bf(r0); outb[o + lane + 64] = f2bf(r1);
    outb[o + lane + 128] = f2bf(r2);
  }
}

// ---------------------------------------------------------------------------
// Fused chain: y = mln(t + res, ln_oX) -> outf; z = mln(y, fln) -> outb.
// ---------------------------------------------------------------------------
__global__ __launch_bounds__(64) void mln_chain_kernel(
    const float* __restrict__ t,
    const float* __restrict__ res0, const float* __restrict__ res1,
    const int* __restrict__ v0, const int* __restrict__ v1,
    const float* __restrict__ g1a, const float* __restrict__ b1a,
    const float* __restrict__ g1b, const float* __restrict__ b1b,
    const float* __restrict__ g2, const float* __restrict__ b2,
    float* __restrict__ outf, ushort_t* __restrict__ outb) {
  int row = blockIdx.x;
  int side = row >= ROWS;
  int r = side ? row - ROWS : row;
  int lane = threadIdx.x;
  const float* tr = t + (size_t)row * DD;
  const float* rr = (side ? res1 : res0) + (size_t)r * DD;
  const float* g1 = side ? g1b : g1a;
  const float* b1 = side ? b1b : b1a;
  int vld = (side ? v1 : v0)[r];
  float v0_ = tr[lane] + rr[lane];
  float v1_ = tr[lane + 64] + rr[lane + 64];
  float v2_ = tr[lane + 128] + rr[lane + 128];
  float s = v0_ + v1_ + v2_;
#pragma unroll
  for (int off = 32; off; off >>= 1) s += __shfl_xor(s, off);
  float mu = s * (1.0f / 192.0f);
  float d0 = v0_ - mu, d1 = v1_ - mu, d2 = v2_ - mu;
  float ss = d0 * d0 + d1 * d1 + d2 * d2;
#pragma unroll
  for (int off = 32; off; off >>= 1) ss += __shfl_xor(ss, off);
  float inv = rsqrtf(ss * (1.0f / 192.0f) + 1e-5f);
  float y0, y1, y2;
  if (vld) {
    y0 = d0 * inv * g1[lane]       + b1[lane];
    y1 = d1 * inv * g1[lane + 64]  + b1[lane + 64];
    y2 = d2 * inv * g1[lane + 128] + b1[lane + 128];
  } else { y0 = v0_; y1 = v1_; y2 = v2_; }
  size_t o = (size_t)row * DD;
  outf[o + lane] = y0; outf[o + lane + 64] = y1; outf[o + lane + 128] = y2;
  float s2 = y0 + y1 + y2;
#pragma unroll
  for (int off = 32; off; off >>= 1) s2 += __shfl_xor(s2, off);
  float mu2 = s2 * (1.0f / 192.0f);
  float e0 = y0 - mu2, e1 = y1 - mu2, e2 = y2 - mu2;
  float ss2 = e0 * e0 + e1 * e1 + e2 * e2;
#pragma unroll
  for (int off = 32; off; off >>= 1) ss2 += __shfl_xor(ss2, off);
  float inv2 = rsqrtf(ss2 * (1.0f / 192.0f) + 1e-5f);
  float z0, z1, z2;
  if (vld) {
    z0 = e0 * inv2 * g2[lane]       + b2[lane];
    z1 = e1 * inv2 * g2[lane + 64]  + b2[lane + 64];
    z2 = e2 * inv2 * g2[lane + 128] + b2[lane + 128];
  } else { z0 = y0; z1 = y1; z2 = y2; }
  outb[o + lane] = f2bf(z0); outb[o + lane + 64] = f2bf(z1);
  outb[o + lane + 128] = f2bf(z2);
}

// ---------------------------------------------------------------------------
// Row-block GEMM for tiny-K projections (K=192 fixed).
// Block = 32 rows x ALL N cols, 256 threads (4 waves), wave w owns cols
// [w*NT*16, (w+1)*NT*16). A staged once in LDS; weights read as pre-swizzled
// coalesced fragments from L2; C staged in LDS then written as fully linear
// per-lane 16B stores (full cache lines -> no write-allocate RMW).
// ---------------------------------------------------------------------------
template <int NT, int F32OUT>
__global__ __launch_bounds__(256) void gemm_rowblk_kernel(
    const ushort_t* __restrict__ A, const ushort_t* __restrict__ Wsw,
    const float* __restrict__ bias, float* __restrict__ Cf,
    ushort_t* __restrict__ Cb) {
  constexpr int N = NT * 64;
  constexpr int CSB = N + 8;            // bf16 staging stride (ushorts)
  constexpr int CSF = N + 4;            // fp32 staging stride (floats)
  constexpr int AS_SH = 32 * 200;       // A staging (ushorts), pad 192->200
  constexpr int CS_SH = F32OUT ? 32 * CSF * 2 : 32 * CSB;
  constexpr int SMEM_SH = AS_SH > CS_SH ? AS_SH : CS_SH;
  __shared__ ushort_t smem[SMEM_SH];
  ushort_t* As = smem;

  int tid = threadIdx.x;
  int w = tid >> 6, lane = tid & 63, l15 = lane & 15, kq = lane >> 4;
  int row0 = blockIdx.x * 32;

  // stage A 32x192 bf16: global is fully linear (192*2 = 24*16B per row)
  {
    const ushort_t* ap = A + (size_t)row0 * 192;
#pragma unroll
    for (int i = 0; i < 3; ++i) {
      int idx = tid + i * 256;
      int r = idx / 24, c = (idx - r * 24) * 8;
      *(uint4*)(&As[r * 200 + c]) = *(const uint4*)(ap + idx * 8);
    }
  }
  __syncthreads();

  f32x4 acc[2][NT];
#pragma unroll
  for (int qs = 0; qs < 2; ++qs)
#pragma unroll
    for (int nt = 0; nt < NT; ++nt) acc[qs][nt] = (f32x4){0.f, 0.f, 0.f, 0.f};

#pragma unroll 1
  for (int kk = 0; kk < 6; ++kk) {
    bf16x8 af[2];
#pragma unroll
    for (int qs = 0; qs < 2; ++qs)
      af[qs] = *(const bf16x8*)(&As[(qs * 16 + l15) * 200 + kk * 32 + kq * 8]);
    const ushort_t* wp =
        Wsw + ((size_t)(kk * (N >> 4) + w * NT) << 9) + lane * 8;
#pragma unroll
    for (int nt = 0; nt < NT; ++nt) {
      U4BF8 wf;
      wf.u = *(const uint4*)(wp + (nt << 9));
#pragma unroll
      for (int qs = 0; qs < 2; ++qs)
        acc[qs][nt] = __builtin_amdgcn_mfma_f32_16x16x32_bf16(
            af[qs], wf.b, acc[qs][nt], 0, 0, 0);
    }
  }
  __syncthreads();  // As dead; smem reused for C staging

  if (!F32OUT) {
    ushort_t* Cs = smem;
#pragma unroll
    for (int nt = 0; nt < NT; ++nt) {
      int col = (w * NT + nt) * 16 + l15;
      float bb = bias[col];
#pragma unroll
      for (int qs = 0; qs < 2; ++qs)
#pragma unroll
        for (int r = 0; r < 4; ++r)
          Cs[(qs * 16 + kq * 4 + r) * CSB + col] = f2bf(acc[qs][nt][r] + bb);
    }
    __syncthreads();
    constexpr int UPR = (N * 2) / 16;   // uint4 per row
#pragma unroll
    for (int i = 0; i < (32 * UPR) / 256; ++i) {
      int idx = tid + i * 256;
      int r = idx / UPR, u = idx - r * UPR;
      *(uint4*)(Cb + (size_t)row0 * N + idx * 8) =
          *(const uint4*)(&Cs[r * CSB + u * 8]);
    }
  } else {
    float* Cs = (float*)smem;
#pragma unroll
    for (int nt = 0; nt < NT; ++nt) {
      int col = (w * NT + nt) * 16 + l15;
      float bb = bias[col];
#pragma unroll
      for (int qs = 0; qs < 2; ++qs)
#pragma unroll
        for (int r = 0; r < 4; ++r)
          Cs[(qs * 16 + kq * 4 + r) * CSF + col] = acc[qs][nt][r] + bb;
    }
    __syncthreads();
    constexpr int UPR = (N * 4) / 16;   // float4 per row
#pragma unroll
    for (int i = 0; i < (32 * UPR) / 256; ++i) {
      int idx = tid + i * 256;
      int r = idx / UPR, u = idx - r * UPR;
      *(float4*)(Cf + (size_t)row0 * N + idx * 4) =
          *(const float4*)(&Cs[r * CSF + u * 4]);
    }
  }
}

// ---------------------------------------------------------------------------
// Fused FFN, v2: 256 threads (4 waves), 64 rows/block, N-split decomposition.
// ---------------------------------------------------------------------------
__global__ __launch_bounds__(256, 3) void ffn_fused_kernel(
    const ushort_t* __restrict__ A, const ushort_t* __restrict__ W1t,
    const float* __restrict__ bias1, const ushort_t* __restrict__ W2t,
    const float* __restrict__ bias2, float* __restrict__ C) {
  __shared__ ushort_t As[64 * 200];      // [row][k], pad 192->200 (25.6 KB)
  __shared__ ushort_t Hs[2][64 * 72];    // shared hidden chunk, dbuf (18.4 KB)
  int tid = threadIdx.x;
  int w = tid >> 6;
  int lane = tid & 63;
  int l15 = lane & 15;
  int kq = lane >> 4;
  int row0 = blockIdx.x * 64;

  // stage A: 64 rows x 24 uint4 = 1536 / 256 threads = 6 each
#pragma unroll
  for (int i = 0; i < 6; ++i) {
    int idx = tid + i * 256;
    int r = idx / 24, c = (idx % 24) * 8;
    *(uint4*)(&As[r * 200 + c]) = *(const uint4*)(A + (size_t)(row0 + r) * DD + c);
  }

  // per-wave weight base pointers
  const ushort_t* w1p = W1t + (size_t)(w * 16 + l15) * DD + kq * 8;
  const ushort_t* w2p = W2t + (size_t)(w * 48 + l15) * HID + kq * 8;

  U4BF8 w1f[6], w1n[6], w2f[6];
#pragma unroll
  for (int kk = 0; kk < 6; ++kk)
    w1f[kk].u = *(const uint4*)(w1p + kk * 32);  // hc = 0

  f32x4 Cacc[4][3];
#pragma unroll
  for (int qs = 0; qs < 4; ++qs)
#pragma unroll
    for (int nt = 0; nt < 3; ++nt) Cacc[qs][nt] = (f32x4){0.f, 0.f, 0.f, 0.f};

  __syncthreads();   // As ready

  for (int hc = 0; hc < 12; ++hc) {
    // issue W2 fragments for this hc early: latency hides under H phase
#pragma unroll
    for (int kk2 = 0; kk2 < 2; ++kk2)
#pragma unroll
      for (int nt = 0; nt < 3; ++nt)
        w2f[kk2 * 3 + nt].u =
            *(const uint4*)(w2p + (size_t)(nt * 16) * HID + hc * 64 + kk2 * 32);

    // --- H[0..63][w*16..+15] = A @ W1 chunk ---
    f32x4 Hacc[4];
#pragma unroll
    for (int qs = 0; qs < 4; ++qs) Hacc[qs] = (f32x4){0.f, 0.f, 0.f, 0.f};
#pragma unroll
    for (int kk = 0; kk < 6; ++kk) {
#pragma unroll
      for (int qs = 0; qs < 4; ++qs) {
        bf16x8 af = *(const bf16x8*)(&As[(qs * 16 + l15) * 200 + kk * 32 + kq * 8]);
        Hacc[qs] = __builtin_amdgcn_mfma_f32_16x16x32_bf16(
            af, w1f[kk].b, Hacc[qs], 0, 0, 0);
      }
    }

    // prefetch next hc's W1 fragments
    if (hc < 11) {
#pragma unroll
      for (int kk = 0; kk < 6; ++kk)
        w1n[kk].u = *(const uint4*)(w1p + (size_t)(hc + 1) * 64 * DD + kk * 32);
    }

    // --- gelu + bias -> Hs[buf] (this wave's 16 columns, all 64 rows) ---
    {
      float bb = bias1[hc * 64 + w * 16 + l15];
      ushort_t* hb = &Hs[hc & 1][0];
#pragma unroll
      for (int qs = 0; qs < 4; ++qs)
#pragma unroll
        for (int r = 0; r < 4; ++r) {
          float x = Hacc[qs][r] + bb;
          x = 0.5f * x * (1.0f + erff(x * 0.70710678118654752f));
          hb[(qs * 16 + kq * 4 + r) * 72 + w * 16 + l15] = f2bf(x);
        }
    }
    __syncthreads();   // Hs[buf] complete; also fences reads of Hs[buf^1]

    // --- C[0..63][w*48..+47] += H @ W2 chunk ---
#pragma unroll
    for (int kk2 = 0; kk2 < 2; ++kk2) {
      bf16x8 hf[4];
#pragma unroll
      for (int qs = 0; qs < 4; ++qs)
        hf[qs] = *(const bf16x8*)(&Hs[hc & 1][(qs * 16 + l15) * 72 + kk2 * 32 + kq * 8]);
#pragma unroll
      for (int nt = 0; nt < 3; ++nt)
#pragma unroll
        for (int qs = 0; qs < 4; ++qs)
          Cacc[qs][nt] = __builtin_amdgcn_mfma_f32_16x16x32_bf16(
              hf[qs], w2f[kk2 * 3 + nt].b, Cacc[qs][nt], 0, 0, 0);
    }

#pragma unroll
    for (int kk = 0; kk < 6; ++kk) w1f[kk] = w1n[kk];
  }

  // epilogue
#pragma unroll
  for (int qs = 0; qs < 4; ++qs)
#pragma unroll
    for (int nt = 0; nt < 3; ++nt) {
      int col = w * 48 + nt * 16 + l15;
      float bb = bias2[col];
#pragma unroll
      for (int r = 0; r < 4; ++r) {
        int row = row0 + qs * 16 + kq * 4 + r;
        C[(size_t)row * DD + col] = Cacc[qs][nt][r] + bb;
      }
    }
}

// ---------------------------------------------------------------------------
// MFMA flash attention (validated R6/R7): both sides, no online max,
// XCD swizzle groups q-tiles of one (b,h,side).
// ---------------------------------------------------------------------------
__global__ __launch_bounds__(256) void attn_mfma_kernel(
    const ushort_t* __restrict__ QKV,
    const int* __restrict__ valid_a, const int* __restrict__ valid_b,
    ushort_t* __restrict__ out) {
  int i = blockIdx.x;
  int gid = ((i >> 5) << 3) | (i & 7);
  int qt = (i >> 3) & 3;
  int side = gid >= BB * HH;
  int grem = side ? gid - BB * HH : gid;
  int h = grem % HH;
  int batch = grem / HH;
  int tid = threadIdx.x;
  int w = tid >> 6;
  int lane = tid & 63;
  int l15 = lane & 15;
  int kq = lane >> 4;

  const int* validq = side ? valid_b : valid_a;
  const int* validk = side ? valid_a : valid_b;
  size_t qrow0  = (size_t)side * ROWS + (size_t)batch * LL;
  size_t kvrow0 = (size_t)(1 - side) * ROWS + (size_t)batch * LL;

  __shared__ ushort_t VsT[32 * 72];
  __shared__ ushort_t Ps[4][32 * 72];

  int qbase = qt * 128 + w * 32;

  U4BF8 qfrag[2];
#pragma unroll
  for (int qs = 0; qs < 2; ++qs)
    qfrag[qs].u = *(const uint4*)(QKV + (qrow0 + qbase + qs * 16 + l15) * 576 +
                                  h * DKK + kq * 8);

  int vq[2][4];
#pragma unroll
  for (int qs = 0; qs < 2; ++qs)
#pragma unroll
    for (int r = 0; r < 4; ++r)
      vq[qs][r] = validq[batch * LL + qbase + qs * 16 + kq * 4 + r];

  float lsum[2][4];
  f32x4 Oacc[2][2];
#pragma unroll
  for (int qs = 0; qs < 2; ++qs) {
#pragma unroll
    for (int r = 0; r < 4; ++r) lsum[qs][r] = 0.0f;
#pragma unroll
    for (int ds = 0; ds < 2; ++ds) Oacc[qs][ds] = (f32x4){0.f, 0.f, 0.f, 0.f};
  }

  for (int c = 0; c < LL; c += 64) {
    __syncthreads();
    uint4 vv = *(const uint4*)(QKV + (kvrow0 + c + lane) * 576 +
                               384 + h * DKK + w * 8);
    uint_t uu[4] = {vv.x, vv.y, vv.z, vv.w};
#pragma unroll
    for (int j = 0; j < 4; ++j) {
      VsT[(w * 8 + 2 * j) * 72 + lane]     = (ushort_t)(uu[j] & 0xffffu);
      VsT[(w * 8 + 2 * j + 1) * 72 + lane] = (ushort_t)(uu[j] >> 16);
    }
    __syncthreads();

    f32x4 S[2][4];
    int vk[4];
#pragma unroll
    for (int ks = 0; ks < 4; ++ks) {
      U4BF8 kf;
      kf.u = *(const uint4*)(QKV + (kvrow0 + c + ks * 16 + l15) * 576 +
                             192 + h * DKK + kq * 8);
      vk[ks] = validk[batch * LL + c + ks * 16 + l15];
#pragma unroll
      for (int qs = 0; qs < 2; ++qs) {
        f32x4 z = (f32x4){0.f, 0.f, 0.f, 0.f};
        S[qs][ks] = __builtin_amdgcn_mfma_f32_16x16x32_bf16(
            qfrag[qs].b, kf.b, z, 0, 0, 0);
      }
    }

#pragma unroll
    for (int qs = 0; qs < 2; ++qs)
#pragma unroll
      for (int ks = 0; ks < 4; ++ks)
#pragma unroll
        for (int r = 0; r < 4; ++r) {
          float x = (vq[qs][r] && vk[ks]) ? S[qs][ks][r] * SCALE_ATT : MASKED_S;
          float p = __expf(x);
          ushort_t pb = f2bf(p);
          lsum[qs][r] += bf2f(pb);
          Ps[w][(qs * 16 + kq * 4 + r) * 72 + ks * 16 + l15] = pb;
        }

#pragma unroll
    for (int kh = 0; kh < 2; ++kh) {
      bf16x8 pf[2], vf[2];
#pragma unroll
      for (int qs = 0; qs < 2; ++qs)
        pf[qs] = *(const bf16x8*)(&Ps[w][(qs * 16 + l15) * 72 + kh * 32 + kq * 8]);
#pragma unroll
      for (int ds = 0; ds < 2; ++ds)
        vf[ds] = *(const bf16x8*)(&VsT[(ds * 16 + l15) * 72 + kh * 32 + kq * 8]);
#pragma unroll
      for (int qs = 0; qs < 2; ++qs)
#pragma unroll
        for (int ds = 0; ds < 2; ++ds)
          Oacc[qs][ds] = __builtin_amdgcn_mfma_f32_16x16x32_bf16(
              pf[qs], vf[ds], Oacc[qs][ds], 0, 0, 0);
    }
  }

#pragma unroll
  for (int qs = 0; qs < 2; ++qs)
#pragma unroll
    for (int r = 0; r < 4; ++r) {
      float sm = lsum[qs][r];
#pragma unroll
      for (int off = 1; off < 16; off <<= 1) sm += __shfl_xor(sm, off);
      lsum[qs][r] = sm;
    }

#pragma unroll
  for (int qs = 0; qs < 2; ++qs)
#pragma unroll
    for (int ds = 0; ds < 2; ++ds)
#pragma unroll
      for (int r = 0; r < 4; ++r) {
        int q = qbase + qs * 16 + kq * 4 + r;
        out[(qrow0 + q) * DD + h * DKK + ds * 16 + l15] =
            f2bf(Oacc[qs][ds][r] / lsum[qs][r]);
      }
}

// ---------------------------------------------------------------------------
extern "C" void kernel_launch(void* const* d_in, const int* in_sizes, int n_in,
                              void* d_out, int out_size, void* d_ws, size_t ws_size,
                              hipStream_t stream) {
  const float* x_a = (const float*)d_in[0];
  const float* x_b = (const float*)d_in[1];
  const int* valid_a = (const int*)d_in[2];
  const int* valid_b = (const int*)d_in[3];
  const float* ln_a_g = (const float*)d_in[4];
  const float* ln_a_b = (const float*)d_in[5];
  const float* ln_b_g = (const float*)d_in[6];
  const float* ln_b_b = (const float*)d_in[7];
  const float* ln_oa_g = (const float*)d_in[8];
  const float* ln_oa_b = (const float*)d_in[9];
  const float* ln_ob_g = (const float*)d_in[10];
  const float* ln_ob_b = (const float*)d_in[11];
  const float* wq = (const float*)d_in[12];
  const float* bq = (const float*)d_in[13];
  const float* wk = (const float*)d_in[14];
  const float* bk = (const float*)d_in[15];
  const float* wv = (const float*)d_in[16];
  const float* bv = (const float*)d_in[17];
  const float* wo = (const float*)d_in[18];
  const float* bo = (const float*)d_in[19];
  const float* fln_g = (const float*)d_in[20];
  const float* fln_b = (const float*)d_in[21];
  const float* flno_g = (const float*)d_in[22];
  const float* flno_b = (const float*)d_in[23];
  const float* w1 = (const float*)d_in[24];
  const float* b1 = (const float*)d_in[25];
  const float* w2 = (const float*)d_in[26];
  const float* b2 = (const float*)d_in[27];

  // Workspace: weights [0, 887040); lnFull/attO bf16 [2R,192] at 887040;
  // QKV bf16 [2R,576] at 19761408; tmp fp32 [2R,192] at 76384512. ~114 MB.
  char* wsb = (char*)d_ws;
  ushort_t* Wqkv = (ushort_t*)wsb;
  ushort_t* Wo_t = Wqkv + 110592;
  ushort_t* W1_t = Wo_t + 36864;
  ushort_t* W2_t = W1_t + 147456;
  float*    bqkv = (float*)(W2_t + 147456);
  ushort_t* lnFull = (ushort_t*)(wsb + 887040);
  ushort_t* attO   = lnFull;
  ushort_t* QKV = (ushort_t*)(wsb + 19761408);
  float* tmp = (float*)(wsb + 76384512);

  float* out_a = (float*)d_out;   // [2R,192] fp32 contiguous

  dim3 b64(64), b128(128), b256(256);
  dim3 gMln(2 * ROWS);
  dim3 gGemm(2 * ROWS / 32);                    // 1536 row-blocks
  dim3 gAttn(BB * HH * 4 * 2);                  // 2304
  dim3 gFFN(2 * ROWS / 64);                     // 768

  hipLaunchKernelGGL(pack_kernel, dim3(1731), b256, 0, stream,
                     wq, wk, wv, wo, w1, w2, bq, bk, bv,
                     Wqkv, Wo_t, W1_t, W2_t, bqkv);

  // 1. pre-LN both sides -> lnFull bf16
  hipLaunchKernelGGL(mln2_kernel, gMln, b64, 0, stream,
                     x_a, x_b, (const float*)nullptr, (const float*)nullptr,
                     valid_a, valid_b, ln_a_g, ln_a_b, ln_b_g, ln_b_b,
                     (float*)nullptr, lnFull);

  // 2. fused QKV, both sides (N=576 = 4 waves x NT=9 tiles)
  hipLaunchKernelGGL((gemm_rowblk_kernel<9, 0>), gGemm, b256, 0, stream,
                     lnFull, Wqkv, bqkv, (float*)nullptr, QKV);

  // 3. attention, both sides
  hipLaunchKernelGGL(attn_mfma_kernel, gAttn, b256, 0, stream,
                     QKV, valid_a, valid_b, attO);

  // 4. O-projection, both sides -> tmp fp32 (N=192 = 4 waves x NT=3)
  hipLaunchKernelGGL((gemm_rowblk_kernel<3, 1>), gGemm, b256, 0, stream,
                     attO, Wo_t, bo, tmp, (ushort_t*)nullptr);

  // 5+6. fused residual-LN -> d_out, FFN pre-LN -> lnFull bf16
  hipLaunchKernelGGL(mln_chain_kernel, gMln, b64, 0, stream,
                     tmp, x_a, x_b, valid_a, valid_b,
                     ln_oa_g, ln_oa_b, ln_ob_g, ln_ob_b, fln_g, fln_b,
                     out_a, lnFull);

  // 7. fused FFN (no hidden round-trip), 4-wave N-split -> tmp fp32
  hipLaunchKernelGGL(ffn_fused_kernel, gFFN, b256, 0, stream,
                     lnFull, W1_t, b1, W2_t, b2, tmp);

  // 8. FFN residual + LN -> d_out
  hipLaunchKernelGGL(mln2_kernel, gMln, b64, 0, stream,
                     tmp, tmp + BLD, out_a, out_a + BLD,
                     valid_a, valid_b, flno_g, flno_b, flno_g, flno_b,
                     out_a, (ushort_t*)nullptr);
}